// Round 2
// baseline (310.620 us; speedup 1.0000x reference)
//
#include <hip/hip_runtime.h>
#include <hip/hip_bf16.h>
#include <cstdint>
#include <cstddef>

// K(x,y) = exp(-0.5*||x-y||^2) + 0.1*(x.y^T + 1)^3
// x,y: (8192, 256) fp32. out: (8192, 8192) fp32.
//
// Round 2 strategy: K=256 makes the 2-barrier LDS K-loop barrier-bound.
// Inputs are only 8 MB in bf16 -> all tile re-reads are L2/LLC hits.
// So: prep writes xb/yb in MFMA *fragment order* (1 KB chunks, byte offset =
// lane*16 == fragment position), and the GEMM loads fragments directly from
// global (coalesced dwordx4, lane-contiguous) with NO LDS and NO barriers.
// Compiler pipelines the fully-unrolled K-loop with fine-grained vmcnt.

#define NROWS 8192
#define DK    256
#define BM    128
#define BN    128

typedef __bf16 bf16_8 __attribute__((ext_vector_type(8)));
typedef float  f32x4  __attribute__((ext_vector_type(4)));
typedef unsigned short us8 __attribute__((ext_vector_type(8)));

__device__ __forceinline__ unsigned short f2bf(float f) {
    unsigned int u = __builtin_bit_cast(unsigned int, f);
    u = (u + 0x7FFFu + ((u >> 16) & 1u)) >> 16;  // round-to-nearest-even
    return (unsigned short)u;
}

// ---------------------------------------------------------------------------
// Prep: fp32 -> bf16 in fragment order + fp32 row norms.
// Fragment layout: matrix is 512 panels (16 rows each) x 8 k-chunks (32 cols).
// Chunk (p,c) is 1 KB at ushort offset (p*8+c)*512; within it, lane
// l = quad*16 + r holds M[p*16+r][c*32+quad*8 .. +8] (16 B).
// Block = 256 threads handles one panel of BOTH x and y.
// Thread t: r = t&15, quad = (t>>4)&3, c0 = t>>6 (and c0+4) -> 16 elems each.
// Chunk writes are perfectly lane-contiguous (wave w writes chunks w, w+4).
// ---------------------------------------------------------------------------
__global__ __launch_bounds__(256) void prep_kernel(
    const float* __restrict__ x, const float* __restrict__ y,
    unsigned short* __restrict__ xb, unsigned short* __restrict__ yb,
    float* __restrict__ x2, float* __restrict__ y2)
{
    const int p    = blockIdx.x;      // panel 0..511
    const int t    = threadIdx.x;
    const int r    = t & 15;
    const int g    = t >> 4;          // 0..15
    const int c0   = g >> 2;          // 0..3 (also handles c0+4)
    const int quad = g & 3;
    const int wave = t >> 6;
    const int lane = t & 63;

    __shared__ float redx[4][16];
    __shared__ float redy[4][16];

    const size_t row = (size_t)p * 16 + r;
    const size_t rb0 = row * DK + c0 * 32 + quad * 8;
    const size_t rb1 = rb0 + 128;                       // chunk c0+4

    const size_t d0 = ((size_t)(p * 8 + c0) * 512) + (size_t)(quad * 16 + r) * 8;
    const size_t d1 = d0 + 4 * 512;

    float sx, sy;
    {
        float4 v0 = *(const float4*)(x + rb0);
        float4 v1 = *(const float4*)(x + rb0 + 4);
        float4 v2 = *(const float4*)(x + rb1);
        float4 v3 = *(const float4*)(x + rb1 + 4);
        us8 h0 = {f2bf(v0.x), f2bf(v0.y), f2bf(v0.z), f2bf(v0.w),
                  f2bf(v1.x), f2bf(v1.y), f2bf(v1.z), f2bf(v1.w)};
        us8 h1 = {f2bf(v2.x), f2bf(v2.y), f2bf(v2.z), f2bf(v2.w),
                  f2bf(v3.x), f2bf(v3.y), f2bf(v3.z), f2bf(v3.w)};
        *(us8*)(xb + d0) = h0;
        *(us8*)(xb + d1) = h1;
        sx = v0.x*v0.x + v0.y*v0.y + v0.z*v0.z + v0.w*v0.w
           + v1.x*v1.x + v1.y*v1.y + v1.z*v1.z + v1.w*v1.w
           + v2.x*v2.x + v2.y*v2.y + v2.z*v2.z + v2.w*v2.w
           + v3.x*v3.x + v3.y*v3.y + v3.z*v3.z + v3.w*v3.w;
    }
    {
        float4 v0 = *(const float4*)(y + rb0);
        float4 v1 = *(const float4*)(y + rb0 + 4);
        float4 v2 = *(const float4*)(y + rb1);
        float4 v3 = *(const float4*)(y + rb1 + 4);
        us8 h0 = {f2bf(v0.x), f2bf(v0.y), f2bf(v0.z), f2bf(v0.w),
                  f2bf(v1.x), f2bf(v1.y), f2bf(v1.z), f2bf(v1.w)};
        us8 h1 = {f2bf(v2.x), f2bf(v2.y), f2bf(v2.z), f2bf(v2.w),
                  f2bf(v3.x), f2bf(v3.y), f2bf(v3.z), f2bf(v3.w)};
        *(us8*)(yb + d0) = h0;
        *(us8*)(yb + d1) = h1;
        sy = v0.x*v0.x + v0.y*v0.y + v0.z*v0.z + v0.w*v0.w
           + v1.x*v1.x + v1.y*v1.y + v1.z*v1.z + v1.w*v1.w
           + v2.x*v2.x + v2.y*v2.y + v2.z*v2.z + v2.w*v2.w
           + v3.x*v3.x + v3.y*v3.y + v3.z*v3.z + v3.w*v3.w;
    }

    // lanes {r, r+16, r+32, r+48} hold partials of row r within this wave
    sx += __shfl_xor(sx, 16); sx += __shfl_xor(sx, 32);
    sy += __shfl_xor(sy, 16); sy += __shfl_xor(sy, 32);
    if (lane < 16) { redx[wave][lane] = sx; redy[wave][lane] = sy; }
    __syncthreads();
    if (t < 16) {
        x2[(size_t)p * 16 + t] = redx[0][t] + redx[1][t] + redx[2][t] + redx[3][t];
    } else if (t < 32) {
        const int rr = t - 16;
        y2[(size_t)p * 16 + rr] = redy[0][rr] + redy[1][rr] + redy[2][rr] + redy[3][rr];
    }
}

// ---------------------------------------------------------------------------
// GEMM + fused epilogue, LDS-free. Block = 256 threads = 4 waves in 2x2,
// each wave owns 64x64 (4x4 of 16x16x32 MFMA). Fragments are loaded straight
// from the fragment-ordered global arrays: lane-contiguous 1 KB per load.
// No __syncthreads anywhere; K-loop fully unrolled for compiler pipelining.
// ---------------------------------------------------------------------------
__global__ __launch_bounds__(256) void gemm_ep_kernel(
    const unsigned short* __restrict__ xb, const unsigned short* __restrict__ yb,
    const float* __restrict__ x2, const float* __restrict__ y2,
    float* __restrict__ out)
{
    const int tid  = threadIdx.x;
    const int wave = tid >> 6;
    const int lane = tid & 63;
    const int bm   = blockIdx.x;
    const int bn   = blockIdx.y;
    const int wm   = (wave & 1) * 64;
    const int wn   = (wave >> 1) * 64;

    // panel stride = 8 chunks * 512 ushort = 4096; chunk stride = 512
    const unsigned short* aB = xb + ((size_t)(bm * 8 + (wm >> 4)) * 8) * 512 + (size_t)lane * 8;
    const unsigned short* bB = yb + ((size_t)(bn * 8 + (wn >> 4)) * 8) * 512 + (size_t)lane * 8;

    f32x4 acc[4][4];
    #pragma unroll
    for (int i = 0; i < 4; ++i)
        #pragma unroll
        for (int j = 0; j < 4; ++j)
            acc[i][j] = (f32x4){0.f, 0.f, 0.f, 0.f};

    #pragma unroll
    for (int c = 0; c < 8; ++c) {
        bf16_8 afr[4], bfr[4];
        #pragma unroll
        for (int i = 0; i < 4; ++i)
            afr[i] = *(const bf16_8*)(aB + i * 4096 + c * 512);
        #pragma unroll
        for (int j = 0; j < 4; ++j)
            bfr[j] = *(const bf16_8*)(bB + j * 4096 + c * 512);
        #pragma unroll
        for (int i = 0; i < 4; ++i)
            #pragma unroll
            for (int j = 0; j < 4; ++j)
                acc[i][j] = __builtin_amdgcn_mfma_f32_16x16x32_bf16(
                    afr[i], bfr[j], acc[i][j], 0, 0, 0);
    }

    // Epilogue. C/D layout: col = lane&15, row = quad*4 + reg (verified R1 pass)
    const int quad  = lane >> 4;
    const int l15   = lane & 15;
    const int mBase = bm * BM + wm + quad * 4;
    const int nBase = bn * BN + wn + l15;

    float y2v[4];
    #pragma unroll
    for (int j = 0; j < 4; ++j) y2v[j] = y2[nBase + j * 16];

    #pragma unroll
    for (int i = 0; i < 4; ++i) {
        #pragma unroll
        for (int r = 0; r < 4; ++r) {
            const int m = mBase + i * 16 + r;
            const float xv = x2[m];
            float* orow = out + (size_t)m * NROWS + nBase;
            #pragma unroll
            for (int j = 0; j < 4; ++j) {
                const float xy = acc[i][j][r];
                float s = xv + y2v[j] - 2.0f * xy;
                s = fmaxf(s, 0.0f);
                const float e = __expf(-0.5f * s);
                const float p = xy + 1.0f;
                orow[j * 16] = fmaf(0.1f, p * p * p, e);
            }
        }
    }
}

// ---------------------------------------------------------------------------
extern "C" void kernel_launch(void* const* d_in, const int* in_sizes, int n_in,
                              void* d_out, int out_size, void* d_ws, size_t ws_size,
                              hipStream_t stream) {
    const float* x = (const float*)d_in[0];
    const float* y = (const float*)d_in[1];
    float* out = (float*)d_out;

    char* ws = (char*)d_ws;
    unsigned short* xb = (unsigned short*)ws;                                  // 4 MB
    unsigned short* yb = (unsigned short*)(ws + (size_t)NROWS * DK * 2);       // 4 MB
    float* x2 = (float*)(ws + (size_t)2 * NROWS * DK * 2);                     // 32 KB
    float* y2 = x2 + NROWS;                                                    // 32 KB

    prep_kernel<<<NROWS / 16, 256, 0, stream>>>(x, y, xb, yb, x2, y2);

    dim3 grid(NROWS / BM, NROWS / BN);
    gemm_ep_kernel<<<grid, 256, 0, stream>>>(xb, yb, x2, y2, out);
}

// Round 3
// 296.765 us; speedup vs baseline: 1.0467x; 1.0467x over previous
//
#include <hip/hip_runtime.h>
#include <hip/hip_bf16.h>
#include <cstdint>
#include <cstddef>

// K(x,y) = exp(-0.5*||x-y||^2) + 0.1*(x.y^T + 1)^3
// x,y: (8192, 256) fp32. out: (8192, 8192) fp32.
//
// R3: LDS-staged MFMA GEMM (R1 structure) with three fixes:
//  1. BK=64 (128 B LDS rows) + XOR swizzle blk^=(row&7) baked into the
//     global_load_lds *source* address -> ds_read_b128 fragment reads are
//     2-way (free) instead of 8-16-way bank conflicted.
//  2. K-loop 8 -> 4 iterations (halves the vmcnt(0)+barrier drain tax).
//  3. blockIdx swizzled into 16x16 super-tiles so resident blocks share a
//     ~2 MB input working set (fits per-XCD L2 under store-stream eviction).

#define NROWS 8192
#define DK    256
#define BM    128
#define BN    128
#define BKK   64

typedef __bf16 bf16_8 __attribute__((ext_vector_type(8)));
typedef float  f32x4  __attribute__((ext_vector_type(4)));

__device__ __forceinline__ unsigned short f2bf(float f) {
    unsigned int u = __builtin_bit_cast(unsigned int, f);
    u = (u + 0x7FFFu + ((u >> 16) & 1u)) >> 16;  // round-to-nearest-even
    return (unsigned short)u;
}

// ---------------------------------------------------------------------------
// Prep: fp32 -> bf16 (row-major) + fp32 row squared-norms.
// One wave per row index (handles x row and y row). 8192 blocks x 64 threads.
// ---------------------------------------------------------------------------
__global__ __launch_bounds__(64) void prep_kernel(
    const float* __restrict__ x, const float* __restrict__ y,
    unsigned short* __restrict__ xb, unsigned short* __restrict__ yb,
    float* __restrict__ x2, float* __restrict__ y2)
{
    const int row  = blockIdx.x;
    const int lane = threadIdx.x;          // 0..63, 4 floats each = 256
    const size_t base = (size_t)row * DK + lane * 4;

    const float4 vx = *(const float4*)(x + base);
    const float4 vy = *(const float4*)(y + base);

    ushort4 hx = make_ushort4(f2bf(vx.x), f2bf(vx.y), f2bf(vx.z), f2bf(vx.w));
    ushort4 hy = make_ushort4(f2bf(vy.x), f2bf(vy.y), f2bf(vy.z), f2bf(vy.w));
    *(ushort4*)(xb + base) = hx;
    *(ushort4*)(yb + base) = hy;

    float sx = vx.x * vx.x + vx.y * vx.y + vx.z * vx.z + vx.w * vx.w;
    float sy = vy.x * vy.x + vy.y * vy.y + vy.z * vy.z + vy.w * vy.w;
    #pragma unroll
    for (int off = 32; off > 0; off >>= 1) {
        sx += __shfl_down(sx, off);
        sy += __shfl_down(sy, off);
    }
    if (lane == 0) {
        x2[row] = sx;
        y2[row] = sy;
    }
}

// ---------------------------------------------------------------------------
// GEMM + fused epilogue. 128x128 tile, 4 waves in 2x2 (64x64 each, 4x4 of
// 16x16x32 MFMA). LDS tiles are 128 rows x 64 cols bf16 (128 B rows) with
// XOR-swizzled 16 B blocks: slot (row, p) holds logical block p ^ (row&7).
// global_load_lds (width 16) stages 1 KB chunks (8 rows); the swizzle is
// applied on the per-lane SOURCE column, dest stays lane-contiguous.
// ---------------------------------------------------------------------------
__global__ __launch_bounds__(256) void gemm_ep_kernel(
    const unsigned short* __restrict__ xb, const unsigned short* __restrict__ yb,
    const float* __restrict__ x2, const float* __restrict__ y2,
    float* __restrict__ out)
{
    __shared__ __align__(16) unsigned short As[BM * BKK];  // 16 KB
    __shared__ __align__(16) unsigned short Bs[BN * BKK];  // 16 KB

    const int tid  = threadIdx.x;
    const int wave = tid >> 6;
    const int lane = tid & 63;

    // 16x16 super-tile block swizzle for L2 locality
    const int id  = blockIdx.x;
    const int sup = id >> 8;           // 0..15
    const int loc = id & 255;
    const int bm  = (sup & 3) * 16 + (loc >> 4);
    const int bn  = (sup >> 2) * 16 + (loc & 15);

    const int wm = (wave & 1) * 64;
    const int wn = (wave >> 1) * 64;

    // --- staging addresses. Wave w stages chunks w*4..w*4+3 of A and B.
    // Chunk = 8 rows x 64 cols = 1 KB. Lane l: row r8 = l>>3, dest block
    // cb = l&7; source column block = cb ^ r8 (the swizzle).
    const int r8 = lane >> 3;
    const int cb = lane & 7;
    const int scol = (cb ^ r8) * 8;    // ushort offset within row

    const unsigned short* gA = xb + (size_t)(bm * BM + wave * 32 + r8) * DK + scol;
    const unsigned short* gB = yb + (size_t)(bn * BN + wave * 32 + r8) * DK + scol;
    unsigned short* lA = &As[wave * 4 * 512 + lane * 8];
    unsigned short* lB = &Bs[wave * 4 * 512 + lane * 8];

    f32x4 acc[4][4];
    #pragma unroll
    for (int i = 0; i < 4; ++i)
        #pragma unroll
        for (int j = 0; j < 4; ++j)
            acc[i][j] = (f32x4){0.f, 0.f, 0.f, 0.f};

    const int quad = lane >> 4;   // 0..3
    const int l15  = lane & 15;
    const int sw   = l15 & 7;     // swizzle term for fragment reads

    for (int kt = 0; kt < 4; ++kt) {
        #pragma unroll
        for (int c = 0; c < 4; ++c) {
            __builtin_amdgcn_global_load_lds(
                (const __attribute__((address_space(1))) void*)(gA + kt * 64 + c * 8 * DK),
                (__attribute__((address_space(3))) void*)(lA + c * 512), 16, 0, 0);
            __builtin_amdgcn_global_load_lds(
                (const __attribute__((address_space(1))) void*)(gB + kt * 64 + c * 8 * DK),
                (__attribute__((address_space(3))) void*)(lB + c * 512), 16, 0, 0);
        }
        __syncthreads();

        // Fragments: A[m=l15][k = s*32 + quad*8 + j], swizzled block lookup
        #pragma unroll
        for (int s = 0; s < 2; ++s) {
            bf16_8 afr[4], bfr[4];
            const int blk = ((s * 4 + quad) ^ sw) * 8;
            #pragma unroll
            for (int i = 0; i < 4; ++i)
                afr[i] = *(const bf16_8*)&As[(wm + i * 16 + l15) * BKK + blk];
            #pragma unroll
            for (int j = 0; j < 4; ++j)
                bfr[j] = *(const bf16_8*)&Bs[(wn + j * 16 + l15) * BKK + blk];
            #pragma unroll
            for (int i = 0; i < 4; ++i)
                #pragma unroll
                for (int j = 0; j < 4; ++j)
                    acc[i][j] = __builtin_amdgcn_mfma_f32_16x16x32_bf16(
                        afr[i], bfr[j], acc[i][j], 0, 0, 0);
        }
        __syncthreads();
    }

    // --- epilogue. C/D layout: col = lane&15, row = quad*4 + reg
    const int mBase = bm * BM + wm + quad * 4;
    const int nBase = bn * BN + wn + l15;

    float y2v[4];
    #pragma unroll
    for (int j = 0; j < 4; ++j) y2v[j] = y2[nBase + j * 16];

    #pragma unroll
    for (int i = 0; i < 4; ++i) {
        #pragma unroll
        for (int r = 0; r < 4; ++r) {
            const int m = mBase + i * 16 + r;
            const float xv = x2[m];
            float* orow = out + (size_t)m * NROWS + nBase;
            #pragma unroll
            for (int j = 0; j < 4; ++j) {
                const float xy = acc[i][j][r];
                float s = xv + y2v[j] - 2.0f * xy;
                s = fmaxf(s, 0.0f);
                const float e = __expf(-0.5f * s);
                const float p = xy + 1.0f;
                orow[j * 16] = fmaf(0.1f, p * p * p, e);
            }
        }
    }
}

// ---------------------------------------------------------------------------
extern "C" void kernel_launch(void* const* d_in, const int* in_sizes, int n_in,
                              void* d_out, int out_size, void* d_ws, size_t ws_size,
                              hipStream_t stream) {
    const float* x = (const float*)d_in[0];
    const float* y = (const float*)d_in[1];
    float* out = (float*)d_out;

    char* ws = (char*)d_ws;
    unsigned short* xb = (unsigned short*)ws;                                  // 4 MB
    unsigned short* yb = (unsigned short*)(ws + (size_t)NROWS * DK * 2);       // 4 MB
    float* x2 = (float*)(ws + (size_t)2 * NROWS * DK * 2);                     // 32 KB
    float* y2 = x2 + NROWS;                                                    // 32 KB

    prep_kernel<<<NROWS, 64, 0, stream>>>(x, y, xb, yb, x2, y2);

    gemm_ep_kernel<<<4096, 256, 0, stream>>>(xb, yb, x2, y2, out);
}